// Round 3
// baseline (1972.479 us; speedup 1.0000x reference)
//
#include <hip/hip_runtime.h>
#include <hip/hip_bf16.h>
#include <cstddef>

#define NN 50000
#define NE 1600000
#define NFEAT 512
#define NHID 512
#define NSSF 256
#define NCLASS 64
#define KTH 8193   // smallest u with count(|ssf|<=u) >= 8193  -> sorted[8192]

typedef unsigned short u16;
typedef unsigned int u32;
typedef u16 u16x8 __attribute__((ext_vector_type(8)));
typedef u16 u16x4 __attribute__((ext_vector_type(4)));
typedef short bf16x8 __attribute__((ext_vector_type(8)));
typedef float f32x4 __attribute__((ext_vector_type(4)));

__device__ __forceinline__ float bf2f(u16 u) {
  union { unsigned u; float f; } c; c.u = ((unsigned)u) << 16; return c.f;
}
__device__ __forceinline__ u16 f2bf(float f) {
  __hip_bfloat16 b = __float2bfloat16(f);   // RNE
  union { __hip_bfloat16 b; u16 u; } c; c.b = b; return c.u;
}

// ---------------- CSR build ----------------------------------------------------------
__global__ void k_hist(const int* __restrict__ dst, int* __restrict__ cnt) {
  int i = blockIdx.x * blockDim.x + threadIdx.x;
  int stride = gridDim.x * blockDim.x;
  for (; i < NE; i += stride) atomicAdd(&cnt[dst[i]], 1);
}

#define SCAN_B 196   // ceil(50000/256)
__global__ void k_blksum(const int* __restrict__ cnt, int* __restrict__ bsum) {
  __shared__ int red[256];
  int b = blockIdx.x, t = threadIdx.x;
  int i = b * 256 + t;
  red[t] = (i < NN) ? cnt[i] : 0;
  __syncthreads();
  for (int s = 128; s > 0; s >>= 1) { if (t < s) red[t] += red[t + s]; __syncthreads(); }
  if (t == 0) bsum[b] = red[0];
}

__global__ void k_scanb(const int* __restrict__ bsum, int* __restrict__ boff,
                        int* __restrict__ rp) {
  __shared__ int buf[256];
  int t = threadIdx.x;
  int x = (t < SCAN_B) ? bsum[t] : 0;
  buf[t] = x;
  __syncthreads();
  for (int off = 1; off < 256; off <<= 1) {
    int y = (t >= off) ? buf[t - off] : 0;
    __syncthreads();
    buf[t] += y;
    __syncthreads();
  }
  if (t < SCAN_B) boff[t] = buf[t] - x;   // exclusive
  if (t == 0) rp[0] = 0;
}

__global__ void k_scanf(const int* __restrict__ cnt, const int* __restrict__ boff,
                        int* __restrict__ rp) {
  __shared__ int buf[256];
  int b = blockIdx.x, t = threadIdx.x;
  int i = b * 256 + t;
  int x = (i < NN) ? cnt[i] : 0;
  buf[t] = x;
  __syncthreads();
  for (int off = 1; off < 256; off <<= 1) {
    int y = (t >= off) ? buf[t - off] : 0;
    __syncthreads();
    buf[t] += y;
    __syncthreads();
  }
  if (i < NN) rp[i + 1] = boff[b] + buf[t];   // inclusive + block offset
}

__global__ void k_copy_int(const int* __restrict__ a, int* __restrict__ b, int n) {
  int i = blockIdx.x * blockDim.x + threadIdx.x;
  if (i < n) b[i] = a[i];
}

// edge meta: low16 = src (NN < 65536), high16 = bf16(val) -> fp32 via mask
__global__ void k_scatter(const int* __restrict__ src, const int* __restrict__ dst,
                          const float* __restrict__ vals, int* __restrict__ fill,
                          u32* __restrict__ em) {
  int i = blockIdx.x * blockDim.x + threadIdx.x;
  int stride = gridDim.x * blockDim.x;
  for (; i < NE; i += stride) {
    int p = atomicAdd(&fill[dst[i]], 1);
    em[p] = (u32)src[i] | ((u32)f2bf(vals[i]) << 16);
  }
}

// ---------------- fp32 -> bf16 bulk convert ------------------------------------------
__global__ void k_cvt_bf16(const float* __restrict__ x, u16* __restrict__ xb, int n4) {
  int i = blockIdx.x * blockDim.x + threadIdx.x;
  if (i < n4) {
    float4 v = *(const float4*)(x + (size_t)i * 4);
    u16x4 o;
    o[0] = f2bf(v.x); o[1] = f2bf(v.y); o[2] = f2bf(v.z); o[3] = f2bf(v.w);
    *(u16x4*)(xb + (size_t)i * 4) = o;
  }
}

// ---------------- W[K][N] fp32 -> Wt[N][K] bf16 --------------------------------------
__global__ void k_wt(const float* __restrict__ W, u16* __restrict__ Wt, int K, int N) {
  int idx = blockIdx.x * blockDim.x + threadIdx.x;
  if (idx < N * K) {
    int n = idx / K, k = idx % K;
    Wt[idx] = f2bf(W[(size_t)k * N + n]);
  }
}

// ---------------- bf16 MFMA GEMM: C[M,N] = bf16(A[M,K] @ Bt[N,K]^T + bias) -----------
__global__ __launch_bounds__(256, 2) void k_gemm_mfma(
    const u16* __restrict__ A, const u16* __restrict__ Bt,
    const float* __restrict__ bias, u16* __restrict__ C,
    int M, int K, int N)
{
  __shared__ __align__(16) u16 As[128 * 32];
  __shared__ __align__(16) u16 Bs[128 * 32];
  int tid = threadIdx.x;
  int bm = blockIdx.y * 128;
  int bn = blockIdx.x * 128;

  int c0 = tid, c1 = tid + 256;
  int ar0 = c0 >> 2, as0 = (c0 & 3) * 8;
  int ar1 = c1 >> 2, as1 = (c1 & 3) * 8;
  bool ok0 = (bm + ar0) < M;
  bool ok1 = (bm + ar1) < M;
  const u16* Ap0 = A + (size_t)(bm + ar0) * K + as0;
  const u16* Ap1 = A + (size_t)(bm + ar1) * K + as1;
  const u16* Bp0 = Bt + (size_t)(bn + ar0) * K + as0;
  const u16* Bp1 = Bt + (size_t)(bn + ar1) * K + as1;

  int wave = tid >> 6, lane = tid & 63;
  int wm = (wave >> 1) * 64, wn = (wave & 1) * 64;
  int m16 = lane & 15, quad = lane >> 4;

  f32x4 zz = {0.f, 0.f, 0.f, 0.f};
  f32x4 acc[4][4];
#pragma unroll
  for (int i = 0; i < 4; i++)
#pragma unroll
    for (int j = 0; j < 4; j++) acc[i][j] = zz;

  u16x8 zv = {0, 0, 0, 0, 0, 0, 0, 0};
  u16x8 a0r = ok0 ? *(const u16x8*)Ap0 : zv;
  u16x8 a1r = ok1 ? *(const u16x8*)Ap1 : zv;
  u16x8 b0r = *(const u16x8*)Bp0;
  u16x8 b1r = *(const u16x8*)Bp1;

  for (int k0 = 0; k0 < K; k0 += 32) {
    __syncthreads();
    *(u16x8*)&As[ar0 * 32 + as0] = a0r;
    *(u16x8*)&As[ar1 * 32 + as1] = a1r;
    *(u16x8*)&Bs[ar0 * 32 + as0] = b0r;
    *(u16x8*)&Bs[ar1 * 32 + as1] = b1r;
    __syncthreads();
    int kn = k0 + 32;
    if (kn < K) {
      a0r = ok0 ? *(const u16x8*)(Ap0 + kn) : zv;
      a1r = ok1 ? *(const u16x8*)(Ap1 + kn) : zv;
      b0r = *(const u16x8*)(Bp0 + kn);
      b1r = *(const u16x8*)(Bp1 + kn);
    }
    bf16x8 af[4], bw[4];
#pragma unroll
    for (int i = 0; i < 4; i++)
      af[i] = *(const bf16x8*)&As[(wm + i * 16 + m16) * 32 + quad * 8];
#pragma unroll
    for (int j = 0; j < 4; j++)
      bw[j] = *(const bf16x8*)&Bs[(wn + j * 16 + m16) * 32 + quad * 8];
#pragma unroll
    for (int i = 0; i < 4; i++)
#pragma unroll
      for (int j = 0; j < 4; j++)
        acc[i][j] = __builtin_amdgcn_mfma_f32_16x16x32_bf16(af[i], bw[j], acc[i][j], 0, 0, 0);
  }

#pragma unroll
  for (int j = 0; j < 4; j++) {
    int col = bn + wn + j * 16 + m16;
    float bv = bias[col];
#pragma unroll
    for (int i = 0; i < 4; i++) {
      int rbase = bm + wm + i * 16 + quad * 4;
#pragma unroll
      for (int r = 0; r < 4; r++) {
        int row = rbase + r;
        if (row < M) C[(size_t)row * N + col] = f2bf(acc[i][j][r] + bv);
      }
    }
  }
}

// ---------------- chunked CSR SPMM: L2-resident 32-feature slices --------------------
// FD = dwords per row (256 for F=512, 128 for F=256). NCH = FD/16 chunks.
// Persistent grid 2048 blocks x 256; chunk-outer loop -> active X slice = 3.2 MB.
// 4 edges per wave-iter: 16 lanes per edge, 1 dword (2 bf16 features) per lane.
template<int FD, int NCH, int RELU, int F32OUT>
__global__ __launch_bounds__(256) void k_spmm_c(
    const int* __restrict__ rp, const u32* __restrict__ em,
    const u32* __restrict__ X, u32* __restrict__ obf, float2* __restrict__ of)
{
  int wid = (blockIdx.x * 256 + threadIdx.x) >> 6;   // global wave 0..8191
  int lane = threadIdx.x & 63;
  int fd = lane & 15;      // dword within chunk
  int eg = lane >> 4;      // edge group 0..3
  const int NW = 2048 * 4;

  for (int c = 0; c < NCH; ++c) {
    int cb = c * 16 + fd;
    for (int r = wid; r < NN; r += NW) {
      int e0 = rp[r], e1 = rp[r + 1];
      float ax = 0.f, ay = 0.f;
      for (int eb = e0; eb < e1; eb += 64) {
        int rem = e1 - eb;
        u32 meta = em[eb + ((lane < rem) ? lane : 0)];
        if (lane >= rem) meta &= 0xFFFFu;            // zero val for dup lanes
        int n4 = (rem < 64) ? rem : 64;
        for (int j = 0; j < n4; j += 4) {
          u32 m = (u32)__shfl((int)meta, j + eg);
          float v = __uint_as_float(m & 0xFFFF0000u);  // bf16 val already high-aligned
          int s = (int)(m & 0xFFFFu);
          u32 xw = X[(size_t)s * FD + cb];
          ax += v * __uint_as_float(xw << 16);
          ay += v * __uint_as_float(xw & 0xFFFF0000u);
        }
      }
      ax += __shfl_xor(ax, 32); ay += __shfl_xor(ay, 32);
      ax += __shfl_xor(ax, 16); ay += __shfl_xor(ay, 16);
      if (eg == 0) {
        if (F32OUT) {
          float2 o; o.x = ax; o.y = ay;
          of[(size_t)r * FD + cb] = o;
        } else {
          if (RELU) { ax = fmaxf(ax, 0.f); ay = fmaxf(ay, 0.f); }
          obf[(size_t)r * FD + cb] = (u32)f2bf(ax) | ((u32)f2bf(ay) << 16);
        }
      }
    }
  }
}

// ---------------- rank-select threshold (LDS-staged) ---------------------------------
__global__ void k_threshold(const float* __restrict__ ssf, float* __restrict__ thr) {
  __shared__ unsigned skey[NSSF * NCLASS];
  __shared__ int red[256];
  int tid = threadIdx.x;
  for (int i = tid; i < NSSF * NCLASS; i += 256)
    skey[i] = __float_as_uint(ssf[i]) & 0x7fffffffu;
  __syncthreads();
  unsigned lo = 0u, hi = 0x7f800000u;
  while (lo < hi) {
    unsigned mid = lo + ((hi - lo) >> 1);
    int c = 0;
    for (int i = tid; i < NSSF * NCLASS; i += 256)
      c += (skey[i] <= mid) ? 1 : 0;
    red[tid] = c;
    __syncthreads();
    for (int s = 128; s > 0; s >>= 1) {
      if (tid < s) red[tid] += red[tid + s];
      __syncthreads();
    }
    int total = red[0];
    __syncthreads();
    if (total >= KTH) hi = mid; else lo = mid + 1;
  }
  if (tid == 0) thr[0] = __uint_as_float(lo);
}

__global__ void k_sparsify(const float* __restrict__ ssf, const float* __restrict__ thr,
                           float* __restrict__ outp) {
  int i = blockIdx.x * blockDim.x + threadIdx.x;
  if (i < NSSF * NCLASS) {
    float v = ssf[i];
    outp[i] = (fabsf(v) >= thr[0]) ? v : 0.f;
  }
}

__global__ void k_colstats(const float* __restrict__ ssf_sp, float* __restrict__ colsq,
                           float* __restrict__ cnorm) {
  int c = threadIdx.x;  // 64
  float s = 0.f;
  for (int k = 0; k < NSSF; k++) {
    float v = ssf_sp[k * NCLASS + c];
    s += v * v;
  }
  colsq[c] = s;
  cnorm[c] = fmaxf(sqrtf(s), 1e-6f);
}

// ---------------- fused epilogue -----------------------------------------------------
__global__ __launch_bounds__(256) void k_final(
    const float* __restrict__ h, const float* __restrict__ ssf_sp,
    const float* __restrict__ colsq, const float* __restrict__ cn,
    float* __restrict__ outp, float* __restrict__ lossp)
{
  __shared__ float s_ssf[NSSF * NCLASS];
  int tid = threadIdx.x;
  for (int i = tid; i < NSSF * NCLASS; i += 256) s_ssf[i] = ssf_sp[i];
  __syncthreads();
  int wave = tid >> 6, lane = tid & 63;

  for (int r = blockIdx.x * 4 + wave; r < NN; r += gridDim.x * 4) {
    float4 hv = *(const float4*)(h + (size_t)r * NSSF + lane * 4);
    float hsq = hv.x * hv.x + hv.y * hv.y + hv.z * hv.z + hv.w * hv.w;
#pragma unroll
    for (int m = 1; m < 64; m <<= 1) hsq += __shfl_xor(hsq, m);

    float acc = 0.f;
    for (int k4 = 0; k4 < 64; ++k4) {
      float hx = __shfl(hv.x, k4);
      float hy = __shfl(hv.y, k4);
      float hz = __shfl(hv.z, k4);
      float hw = __shfl(hv.w, k4);
      const float* p = &s_ssf[k4 * 4 * NCLASS + lane];
      acc += hx * p[0] + hy * p[NCLASS] + hz * p[2 * NCLASS] + hw * p[3 * NCLASS];
    }
    float o = acc;
    outp[(size_t)r * NCLASS + lane] = o;

    float sq = hsq - 2.f * o + colsq[lane];
    float d = -sqrtf(fmaxf(sq, 1e-12f));
    float hn = fmaxf(sqrtf(hsq), 1e-6f);
    float sim = o / (hn * cn[lane]);

    float m1 = d;
#pragma unroll
    for (int m = 1; m < 64; m <<= 1) m1 = fmaxf(m1, __shfl_xor(m1, m));
    float s1 = expf(d - m1);
#pragma unroll
    for (int m = 1; m < 64; m <<= 1) s1 += __shfl_xor(s1, m);
    float ls1 = d - m1 - logf(s1);

    float m2 = sim;
#pragma unroll
    for (int m = 1; m < 64; m <<= 1) m2 = fmaxf(m2, __shfl_xor(m2, m));
    float s2 = expf(sim - m2);
#pragma unroll
    for (int m = 1; m < 64; m <<= 1) s2 += __shfl_xor(s2, m);
    float ls2 = sim - m2 - logf(s2);

    lossp[(size_t)r * NCLASS + lane] = 0.5f * (ls1 + ls2);
  }
}

__global__ void k_copy_sigma(const float* __restrict__ s, float* __restrict__ o) {
  o[0] = s[0];
}

extern "C" void kernel_launch(void* const* d_in, const int* in_sizes, int n_in,
                              void* d_out, int out_size, void* d_ws, size_t ws_size,
                              hipStream_t stream)
{
  (void)in_sizes; (void)n_in; (void)out_size; (void)ws_size;
  const float* x    = (const float*)d_in[0];
  const int*   src  = (const int*)  d_in[1];
  const int*   dst  = (const int*)  d_in[2];
  const float* vals = (const float*)d_in[3];
  const float* W1 = (const float*)d_in[4];
  const float* b1 = (const float*)d_in[5];
  const float* W2 = (const float*)d_in[6];
  const float* b2 = (const float*)d_in[7];
  const float* W3 = (const float*)d_in[8];
  const float* b3 = (const float*)d_in[9];
  const float* ssf   = (const float*)d_in[10];
  const float* sigma = (const float*)d_in[11];

  // output layout: out[50000,64] | ssf_sp[256,64] | h[50000,256] | loss[50000,64] | sigma
  float* outf   = (float*)d_out;
  float* o_out  = outf;
  float* o_ssf  = outf + (size_t)NN * NCLASS;
  float* o_h    = o_ssf + NSSF * NCLASS;
  float* o_loss = o_h + (size_t)NN * NSSF;
  float* o_sig  = o_loss + (size_t)NN * NCLASS;

  // workspace
  u16* Xb  = (u16*)d_ws;                       // [NN,512] bf16
  u16* Yb  = Xb + (size_t)NN * NFEAT;          // [NN,512]
  u16* Hb  = Yb + (size_t)NN * NHID;           // [NN,512]
  u16* W1t = Hb + (size_t)NN * NHID;
  u16* W2t = W1t + (size_t)NFEAT * NHID;
  u16* W3t = W2t + (size_t)NHID * NHID;
  int* cnt = (int*)(W3t + (size_t)NSSF * NHID);
  int* rp  = cnt + NN;
  u32* em  = (u32*)(rp + 50016);
  int* bsum = (int*)(em + NE);
  int* boff = bsum + 256;
  float* thr = (float*)(boff + 256);
  float* csq = thr + 16;
  float* cnm = csq + 64;

  // CSR build
  hipMemsetAsync(cnt, 0, NN * sizeof(int), stream);
  k_hist<<<1024, 256, 0, stream>>>(dst, cnt);
  k_blksum<<<SCAN_B, 256, 0, stream>>>(cnt, bsum);
  k_scanb<<<1, 256, 0, stream>>>(bsum, boff, rp);
  k_scanf<<<SCAN_B, 256, 0, stream>>>(cnt, boff, rp);
  k_copy_int<<<(NN + 255) / 256, 256, 0, stream>>>(rp, cnt, NN);  // cnt -> fill
  k_scatter<<<1024, 256, 0, stream>>>(src, dst, vals, cnt, em);

  // bf16 conversions
  k_cvt_bf16<<<(NN * NFEAT / 4 + 255) / 256, 256, 0, stream>>>(x, Xb, NN * NFEAT / 4);
  k_wt<<<(NFEAT * NHID + 255) / 256, 256, 0, stream>>>(W1, W1t, NFEAT, NHID);
  k_wt<<<(NHID * NHID + 255) / 256, 256, 0, stream>>>(W2, W2t, NHID, NHID);
  k_wt<<<(NHID * NSSF + 255) / 256, 256, 0, stream>>>(W3, W3t, NHID, NSSF);

  // 3 GCN layers
  k_gemm_mfma<<<dim3(4, 391), 256, 0, stream>>>(Xb, W1t, b1, Yb, NN, NFEAT, NHID);
  k_spmm_c<256, 16, 1, 0><<<2048, 256, 0, stream>>>(rp, em, (const u32*)Yb, (u32*)Hb, nullptr);
  k_gemm_mfma<<<dim3(4, 391), 256, 0, stream>>>(Hb, W2t, b2, Yb, NN, NHID, NHID);
  k_spmm_c<256, 16, 1, 0><<<2048, 256, 0, stream>>>(rp, em, (const u32*)Yb, (u32*)Xb, nullptr);
  k_gemm_mfma<<<dim3(2, 391), 256, 0, stream>>>(Xb, W3t, b3, Yb, NN, NHID, NSSF);
  k_spmm_c<128, 8, 0, 1><<<2048, 256, 0, stream>>>(rp, em, (const u32*)Yb, nullptr, (float2*)o_h);

  // SSF sparsify + epilogue
  k_threshold<<<1, 256, 0, stream>>>(ssf, thr);
  k_sparsify<<<(NSSF * NCLASS + 255) / 256, 256, 0, stream>>>(ssf, thr, o_ssf);
  k_colstats<<<1, 64, 0, stream>>>(o_ssf, csq, cnm);
  k_final<<<512, 256, 0, stream>>>(o_h, o_ssf, csq, cnm, o_out, o_loss);
  k_copy_sigma<<<1, 1, 0, stream>>>(sigma, o_sig);
}

// Round 4
// 1346.371 us; speedup vs baseline: 1.4650x; 1.4650x over previous
//
#include <hip/hip_runtime.h>
#include <hip/hip_bf16.h>
#include <cstddef>

#define NN 50000
#define NE 1600000
#define NFEAT 512
#define NHID 512
#define NSSF 256
#define NCLASS 64
#define KTH 8193   // smallest u with count(|ssf|<=u) >= 8193  -> sorted[8192]

typedef unsigned short u16;
typedef unsigned int u32;
typedef u16 u16x8 __attribute__((ext_vector_type(8)));
typedef u16 u16x4 __attribute__((ext_vector_type(4)));
typedef short bf16x8 __attribute__((ext_vector_type(8)));
typedef float f32x4 __attribute__((ext_vector_type(4)));

__device__ __forceinline__ float bf2f(u16 u) {
  union { unsigned u; float f; } c; c.u = ((unsigned)u) << 16; return c.f;
}
__device__ __forceinline__ u16 f2bf(float f) {
  __hip_bfloat16 b = __float2bfloat16(f);   // RNE
  union { __hip_bfloat16 b; u16 u; } c; c.b = b; return c.u;
}

// async global->LDS, 16B per lane, dest = uniform base + lane*16
__device__ __forceinline__ void async_load16(const void* g, void* l) {
  __builtin_amdgcn_global_load_lds(
      (const __attribute__((address_space(1))) unsigned int*)g,
      (__attribute__((address_space(3))) unsigned int*)l, 16, 0, 0);
}

// ---------------- CSR build ----------------------------------------------------------
__global__ void k_hist(const int* __restrict__ dst, int* __restrict__ cnt) {
  int i = blockIdx.x * blockDim.x + threadIdx.x;
  int stride = gridDim.x * blockDim.x;
  for (; i < NE; i += stride) atomicAdd(&cnt[dst[i]], 1);
}

#define SCAN_B 196   // ceil(50000/256)
__global__ void k_blksum(const int* __restrict__ cnt, int* __restrict__ bsum) {
  __shared__ int red[256];
  int b = blockIdx.x, t = threadIdx.x;
  int i = b * 256 + t;
  red[t] = (i < NN) ? cnt[i] : 0;
  __syncthreads();
  for (int s = 128; s > 0; s >>= 1) { if (t < s) red[t] += red[t + s]; __syncthreads(); }
  if (t == 0) bsum[b] = red[0];
}

__global__ void k_scanb(const int* __restrict__ bsum, int* __restrict__ boff,
                        int* __restrict__ rp) {
  __shared__ int buf[256];
  int t = threadIdx.x;
  int x = (t < SCAN_B) ? bsum[t] : 0;
  buf[t] = x;
  __syncthreads();
  for (int off = 1; off < 256; off <<= 1) {
    int y = (t >= off) ? buf[t - off] : 0;
    __syncthreads();
    buf[t] += y;
    __syncthreads();
  }
  if (t < SCAN_B) boff[t] = buf[t] - x;   // exclusive
  if (t == 0) rp[0] = 0;
}

// writes rp (inclusive, shifted) AND fill[] = exclusive prefix (for scatter)
__global__ void k_scanf(const int* __restrict__ cnt, const int* __restrict__ boff,
                        int* __restrict__ rp, int* __restrict__ fill) {
  __shared__ int buf[256];
  int b = blockIdx.x, t = threadIdx.x;
  int i = b * 256 + t;
  int x = (i < NN) ? cnt[i] : 0;
  buf[t] = x;
  __syncthreads();
  for (int off = 1; off < 256; off <<= 1) {
    int y = (t >= off) ? buf[t - off] : 0;
    __syncthreads();
    buf[t] += y;
    __syncthreads();
  }
  if (i < NN) {
    int incl = boff[b] + buf[t];
    rp[i + 1] = incl;
    fill[i] = incl - x;
  }
}

// edge meta: low16 = src (NN < 65536), high16 = bf16(val) -> fp32 via mask
__global__ void k_scatter(const int* __restrict__ src, const int* __restrict__ dst,
                          const float* __restrict__ vals, int* __restrict__ fill,
                          u32* __restrict__ em) {
  int i = blockIdx.x * blockDim.x + threadIdx.x;
  int stride = gridDim.x * blockDim.x;
  for (; i < NE; i += stride) {
    int p = atomicAdd(&fill[dst[i]], 1);
    em[p] = (u32)src[i] | ((u32)f2bf(vals[i]) << 16);
  }
}

// ---------------- fp32 -> bf16 bulk convert ------------------------------------------
__global__ void k_cvt_bf16(const float* __restrict__ x, u16* __restrict__ xb, int n4) {
  int i = blockIdx.x * blockDim.x + threadIdx.x;
  if (i < n4) {
    float4 v = *(const float4*)(x + (size_t)i * 4);
    u16x4 o;
    o[0] = f2bf(v.x); o[1] = f2bf(v.y); o[2] = f2bf(v.z); o[3] = f2bf(v.w);
    *(u16x4*)(xb + (size_t)i * 4) = o;
  }
}

// ---------------- W[K][N] fp32 -> Wt[N][K] bf16 --------------------------------------
__global__ void k_wt(const float* __restrict__ W, u16* __restrict__ Wt, int K, int N) {
  int idx = blockIdx.x * blockDim.x + threadIdx.x;
  if (idx < N * K) {
    int n = idx / K, k = idx % K;
    Wt[idx] = f2bf(W[(size_t)k * N + n]);
  }
}

// ---------------- bf16 MFMA GEMM (m97 pattern): C = bf16(A @ Bt^T + bias) ------------
// 128x128 tile, BK=32, 256 thr = 4 waves (2x2 of 64x64), global_load_lds staging.
__global__ __launch_bounds__(256, 2) void k_gemm_mfma(
    const u16* __restrict__ A, const u16* __restrict__ Bt,
    const float* __restrict__ bias, u16* __restrict__ C,
    int M, int K, int N)
{
  __shared__ __align__(16) u16 As[128 * 32];   // row-major [128][32]
  __shared__ __align__(16) u16 Bs[128 * 32];
  int tid = threadIdx.x;
  int bm = blockIdx.y * 128;
  int bn = blockIdx.x * 128;
  int wave = tid >> 6, lane = tid & 63;

  // staging: each wave covers 32 rows of As (2 chunks of 16 rows) + 32 rows of Bs.
  // chunk = 16 rows x 64B = 1KB = 64 lanes x 16B. lane l: row=l>>2, col8=(l&3)*8.
  int lrow = lane >> 2, lcol = (lane & 3) * 8;
  int arow0 = wave * 32 + lrow;        // chunk 0 rows
  int arow1 = wave * 32 + 16 + lrow;   // chunk 1 rows
  int garow0 = bm + arow0; if (garow0 >= M) garow0 = M - 1;   // clamp (tail tile)
  int garow1 = bm + arow1; if (garow1 >= M) garow1 = M - 1;
  const u16* Ap0 = A + (size_t)garow0 * K + lcol;
  const u16* Ap1 = A + (size_t)garow1 * K + lcol;
  const u16* Bp0 = Bt + (size_t)(bn + arow0) * K + lcol;
  const u16* Bp1 = Bt + (size_t)(bn + arow1) * K + lcol;
  u16* lA0 = &As[(wave * 32) * 32];
  u16* lA1 = &As[(wave * 32 + 16) * 32];
  u16* lB0 = &Bs[(wave * 32) * 32];
  u16* lB1 = &Bs[(wave * 32 + 16) * 32];

  int wm = (wave >> 1) * 64, wn = (wave & 1) * 64;
  int m16 = lane & 15, quad = lane >> 4;

  f32x4 zz = {0.f, 0.f, 0.f, 0.f};
  f32x4 acc[4][4];
#pragma unroll
  for (int i = 0; i < 4; i++)
#pragma unroll
    for (int j = 0; j < 4; j++) acc[i][j] = zz;

  for (int k0 = 0; k0 < K; k0 += 32) {
    // previous iteration's reads are complete (barrier at loop end)
    async_load16(Ap0 + k0, lA0);
    async_load16(Ap1 + k0, lA1);
    async_load16(Bp0 + k0, lB0);
    async_load16(Bp1 + k0, lB1);
    __syncthreads();   // drains vmcnt(0): staged data visible to all

    bf16x8 af[4], bw[4];
#pragma unroll
    for (int i = 0; i < 4; i++)
      af[i] = *(const bf16x8*)&As[(wm + i * 16 + m16) * 32 + quad * 8];
#pragma unroll
    for (int j = 0; j < 4; j++)
      bw[j] = *(const bf16x8*)&Bs[(wn + j * 16 + m16) * 32 + quad * 8];
#pragma unroll
    for (int i = 0; i < 4; i++)
#pragma unroll
      for (int j = 0; j < 4; j++)
        acc[i][j] = __builtin_amdgcn_mfma_f32_16x16x32_bf16(af[i], bw[j], acc[i][j], 0, 0, 0);
    __syncthreads();   // all reads done before next stage overwrites
  }

#pragma unroll
  for (int j = 0; j < 4; j++) {
    int col = bn + wn + j * 16 + m16;
    float bv = bias[col];
#pragma unroll
    for (int i = 0; i < 4; i++) {
      int rbase = bm + wm + i * 16 + quad * 4;
#pragma unroll
      for (int r = 0; r < 4; r++) {
        int row = rbase + r;
        if (row < M) C[(size_t)row * N + col] = f2bf(acc[i][j][r] + bv);
      }
    }
  }
}

// ---------------- CSR SPMM F=512: bf16 gather, fp32 acc, unroll-2, relu --------------
__global__ __launch_bounds__(256) void k_spmm512(
    const int* __restrict__ rp, const u32* __restrict__ em,
    const u16* __restrict__ Xb, u16* __restrict__ Hb)
{
  int wave = threadIdx.x >> 6, lane = threadIdx.x & 63;
  int r = blockIdx.x * 4 + wave;
  if (r >= NN) return;
  int e0 = rp[r], e1 = rp[r + 1];
  float acc0[8], acc1[8];
#pragma unroll
  for (int j = 0; j < 8; j++) { acc0[j] = 0.f; acc1[j] = 0.f; }
  const u16* Xl = Xb + lane * 8;
  int e = e0;
  for (; e + 2 <= e1; e += 2) {
    u32 m0 = em[e], m1 = em[e + 1];
    float v0 = __uint_as_float(m0 & 0xFFFF0000u);
    float v1 = __uint_as_float(m1 & 0xFFFF0000u);
    u16x8 x0 = *(const u16x8*)(Xl + (size_t)(m0 & 0xFFFFu) * 512);
    u16x8 x1 = *(const u16x8*)(Xl + (size_t)(m1 & 0xFFFFu) * 512);
#pragma unroll
    for (int j = 0; j < 8; j++) {
      acc0[j] += v0 * bf2f(x0[j]);
      acc1[j] += v1 * bf2f(x1[j]);
    }
  }
  if (e < e1) {
    u32 m0 = em[e];
    float v0 = __uint_as_float(m0 & 0xFFFF0000u);
    u16x8 x0 = *(const u16x8*)(Xl + (size_t)(m0 & 0xFFFFu) * 512);
#pragma unroll
    for (int j = 0; j < 8; j++) acc0[j] += v0 * bf2f(x0[j]);
  }
  u16x8 o;
#pragma unroll
  for (int j = 0; j < 8; j++) o[j] = f2bf(fmaxf(acc0[j] + acc1[j], 0.f));
  *(u16x8*)(Hb + (size_t)r * 512 + lane * 8) = o;
}

// ---------------- CSR SPMM F=256: bf16 gather, fp32 out, no relu ---------------------
__global__ __launch_bounds__(256) void k_spmm256(
    const int* __restrict__ rp, const u32* __restrict__ em,
    const u16* __restrict__ Xb, float* __restrict__ Hf)
{
  int wave = threadIdx.x >> 6, lane = threadIdx.x & 63;
  int r = blockIdx.x * 4 + wave;
  if (r >= NN) return;
  int e0 = rp[r], e1 = rp[r + 1];
  float4 a0 = make_float4(0.f, 0.f, 0.f, 0.f);
  float4 a1 = make_float4(0.f, 0.f, 0.f, 0.f);
  const u16* Xl = Xb + lane * 4;
  int e = e0;
  for (; e + 2 <= e1; e += 2) {
    u32 m0 = em[e], m1 = em[e + 1];
    float v0 = __uint_as_float(m0 & 0xFFFF0000u);
    float v1 = __uint_as_float(m1 & 0xFFFF0000u);
    u16x4 x0 = *(const u16x4*)(Xl + (size_t)(m0 & 0xFFFFu) * 256);
    u16x4 x1 = *(const u16x4*)(Xl + (size_t)(m1 & 0xFFFFu) * 256);
    a0.x += v0 * bf2f(x0[0]); a0.y += v0 * bf2f(x0[1]);
    a0.z += v0 * bf2f(x0[2]); a0.w += v0 * bf2f(x0[3]);
    a1.x += v1 * bf2f(x1[0]); a1.y += v1 * bf2f(x1[1]);
    a1.z += v1 * bf2f(x1[2]); a1.w += v1 * bf2f(x1[3]);
  }
  if (e < e1) {
    u32 m0 = em[e];
    float v0 = __uint_as_float(m0 & 0xFFFF0000u);
    u16x4 x0 = *(const u16x4*)(Xl + (size_t)(m0 & 0xFFFFu) * 256);
    a0.x += v0 * bf2f(x0[0]); a0.y += v0 * bf2f(x0[1]);
    a0.z += v0 * bf2f(x0[2]); a0.w += v0 * bf2f(x0[3]);
  }
  float4 o;
  o.x = a0.x + a1.x; o.y = a0.y + a1.y; o.z = a0.z + a1.z; o.w = a0.w + a1.w;
  *(float4*)(Hf + (size_t)r * 256 + lane * 4) = o;
}

// ---------------- fused ssf: threshold + sparsify + colstats + sigma -----------------
__global__ void k_ssf(const float* __restrict__ ssf, const float* __restrict__ sigma,
                      float* __restrict__ o_ssf, float* __restrict__ csq,
                      float* __restrict__ cnm, float* __restrict__ o_sig)
{
  __shared__ float sv[NSSF * NCLASS];   // 64 KB
  __shared__ int red[256];
  int tid = threadIdx.x;
  for (int i = tid; i < NSSF * NCLASS; i += 256) sv[i] = ssf[i];
  __syncthreads();
  unsigned lo = 0u, hi = 0x7f800000u;
  while (lo < hi) {
    unsigned mid = lo + ((hi - lo) >> 1);
    int c = 0;
    for (int i = tid; i < NSSF * NCLASS; i += 256)
      c += ((__float_as_uint(sv[i]) & 0x7fffffffu) <= mid) ? 1 : 0;
    red[tid] = c;
    __syncthreads();
    for (int s = 128; s > 0; s >>= 1) {
      if (tid < s) red[tid] += red[tid + s];
      __syncthreads();
    }
    int total = red[0];
    __syncthreads();
    if (total >= KTH) hi = mid; else lo = mid + 1;
  }
  float t = __uint_as_float(lo);
  for (int i = tid; i < NSSF * NCLASS; i += 256) {
    float v = sv[i];
    v = (fabsf(v) >= t) ? v : 0.f;
    sv[i] = v;
    o_ssf[i] = v;
  }
  __syncthreads();
  if (tid < 64) {
    float s = 0.f;
    for (int k = 0; k < NSSF; k++) { float v = sv[k * NCLASS + tid]; s += v * v; }
    csq[tid] = s;
    cnm[tid] = fmaxf(sqrtf(s), 1e-6f);
  }
  if (tid == 0) o_sig[0] = sigma[0];
}

// ---------------- fused epilogue -----------------------------------------------------
__global__ __launch_bounds__(256) void k_final(
    const float* __restrict__ h, const float* __restrict__ ssf_sp,
    const float* __restrict__ colsq, const float* __restrict__ cn,
    float* __restrict__ outp, float* __restrict__ lossp)
{
  __shared__ float s_ssf[NSSF * NCLASS];
  int tid = threadIdx.x;
  for (int i = tid; i < NSSF * NCLASS; i += 256) s_ssf[i] = ssf_sp[i];
  __syncthreads();
  int wave = tid >> 6, lane = tid & 63;

  for (int r = blockIdx.x * 4 + wave; r < NN; r += gridDim.x * 4) {
    float4 hv = *(const float4*)(h + (size_t)r * NSSF + lane * 4);
    float hsq = hv.x * hv.x + hv.y * hv.y + hv.z * hv.z + hv.w * hv.w;
#pragma unroll
    for (int m = 1; m < 64; m <<= 1) hsq += __shfl_xor(hsq, m);

    float acc = 0.f;
    for (int k4 = 0; k4 < 64; ++k4) {
      float hx = __shfl(hv.x, k4);
      float hy = __shfl(hv.y, k4);
      float hz = __shfl(hv.z, k4);
      float hw = __shfl(hv.w, k4);
      const float* p = &s_ssf[k4 * 4 * NCLASS + lane];
      acc += hx * p[0] + hy * p[NCLASS] + hz * p[2 * NCLASS] + hw * p[3 * NCLASS];
    }
    float o = acc;
    outp[(size_t)r * NCLASS + lane] = o;

    float sq = hsq - 2.f * o + colsq[lane];
    float d = -sqrtf(fmaxf(sq, 1e-12f));
    float hn = fmaxf(sqrtf(hsq), 1e-6f);
    float sim = o / (hn * cn[lane]);

    float m1 = d;
#pragma unroll
    for (int m = 1; m < 64; m <<= 1) m1 = fmaxf(m1, __shfl_xor(m1, m));
    float s1 = expf(d - m1);
#pragma unroll
    for (int m = 1; m < 64; m <<= 1) s1 += __shfl_xor(s1, m);
    float ls1 = d - m1 - logf(s1);

    float m2 = sim;
#pragma unroll
    for (int m = 1; m < 64; m <<= 1) m2 = fmaxf(m2, __shfl_xor(m2, m));
    float s2 = expf(sim - m2);
#pragma unroll
    for (int m = 1; m < 64; m <<= 1) s2 += __shfl_xor(s2, m);
    float ls2 = sim - m2 - logf(s2);

    lossp[(size_t)r * NCLASS + lane] = 0.5f * (ls1 + ls2);
  }
}

extern "C" void kernel_launch(void* const* d_in, const int* in_sizes, int n_in,
                              void* d_out, int out_size, void* d_ws, size_t ws_size,
                              hipStream_t stream)
{
  (void)in_sizes; (void)n_in; (void)out_size; (void)ws_size;
  const float* x    = (const float*)d_in[0];
  const int*   src  = (const int*)  d_in[1];
  const int*   dst  = (const int*)  d_in[2];
  const float* vals = (const float*)d_in[3];
  const float* W1 = (const float*)d_in[4];
  const float* b1 = (const float*)d_in[5];
  const float* W2 = (const float*)d_in[6];
  const float* b2 = (const float*)d_in[7];
  const float* W3 = (const float*)d_in[8];
  const float* b3 = (const float*)d_in[9];
  const float* ssf   = (const float*)d_in[10];
  const float* sigma = (const float*)d_in[11];

  // output layout: out[50000,64] | ssf_sp[256,64] | h[50000,256] | loss[50000,64] | sigma
  float* outf   = (float*)d_out;
  float* o_out  = outf;
  float* o_ssf  = outf + (size_t)NN * NCLASS;
  float* o_h    = o_ssf + NSSF * NCLASS;
  float* o_loss = o_h + (size_t)NN * NSSF;
  float* o_sig  = o_loss + (size_t)NN * NCLASS;

  // workspace
  u16* Xb  = (u16*)d_ws;                       // [NN,512] bf16
  u16* Yb  = Xb + (size_t)NN * NFEAT;          // [NN,512]
  u16* Hb  = Yb + (size_t)NN * NHID;           // [NN,512]
  u16* W1t = Hb + (size_t)NN * NHID;
  u16* W2t = W1t + (size_t)NFEAT * NHID;
  u16* W3t = W2t + (size_t)NHID * NHID;
  int* cnt = (int*)(W3t + (size_t)NSSF * NHID);
  int* rp  = cnt + NN;
  u32* em  = (u32*)(rp + 50016);
  int* bsum = (int*)(em + NE);
  int* boff = bsum + 256;
  float* csq = (float*)(boff + 256);
  float* cnm = csq + 64;

  // CSR build
  hipMemsetAsync(cnt, 0, NN * sizeof(int), stream);
  k_hist<<<1024, 256, 0, stream>>>(dst, cnt);
  k_blksum<<<SCAN_B, 256, 0, stream>>>(cnt, bsum);
  k_scanb<<<1, 256, 0, stream>>>(bsum, boff, rp);
  k_scanf<<<SCAN_B, 256, 0, stream>>>(cnt, boff, rp, cnt);  // cnt -> fill (in place)
  k_scatter<<<1024, 256, 0, stream>>>(src, dst, vals, cnt, em);

  // bf16 conversions
  k_cvt_bf16<<<(NN * NFEAT / 4 + 255) / 256, 256, 0, stream>>>(x, Xb, NN * NFEAT / 4);
  k_wt<<<(NFEAT * NHID + 255) / 256, 256, 0, stream>>>(W1, W1t, NFEAT, NHID);
  k_wt<<<(NHID * NHID + 255) / 256, 256, 0, stream>>>(W2, W2t, NHID, NHID);
  k_wt<<<(NHID * NSSF + 255) / 256, 256, 0, stream>>>(W3, W3t, NHID, NSSF);

  // 3 GCN layers
  k_gemm_mfma<<<dim3(4, 391), 256, 0, stream>>>(Xb, W1t, b1, Yb, NN, NFEAT, NHID);
  k_spmm512<<<NN / 4, 256, 0, stream>>>(rp, em, Yb, Hb);
  k_gemm_mfma<<<dim3(4, 391), 256, 0, stream>>>(Hb, W2t, b2, Yb, NN, NHID, NHID);
  k_spmm512<<<NN / 4, 256, 0, stream>>>(rp, em, Yb, Xb);   // Xb reused as H2
  k_gemm_mfma<<<dim3(2, 391), 256, 0, stream>>>(Xb, W3t, b3, Yb, NN, NHID, NSSF);
  k_spmm256<<<NN / 4, 256, 0, stream>>>(rp, em, Yb, o_h);

  // SSF sparsify + epilogue
  k_ssf<<<1, 256, 0, stream>>>(ssf, sigma, o_ssf, csq, cnm, o_sig);
  k_final<<<512, 256, 0, stream>>>(o_h, o_ssf, csq, cnm, o_out, o_loss);
}

// Round 5
// 1175.384 us; speedup vs baseline: 1.6782x; 1.1455x over previous
//
#include <hip/hip_runtime.h>
#include <hip/hip_bf16.h>
#include <cstddef>

#define NN 50000
#define NE 1600000
#define NFEAT 512
#define NHID 512
#define NSSF 256
#define NCLASS 64
#define KTH 8193   // smallest u with count(|ssf|<=u) >= 8193  -> sorted[8192]

typedef unsigned short u16;
typedef unsigned int u32;
typedef u16 u16x8 __attribute__((ext_vector_type(8)));
typedef u16 u16x4 __attribute__((ext_vector_type(4)));
typedef short bf16x8 __attribute__((ext_vector_type(8)));
typedef float f32x4 __attribute__((ext_vector_type(4)));

__device__ __forceinline__ float bf2f(u16 u) {
  union { unsigned u; float f; } c; c.u = ((unsigned)u) << 16; return c.f;
}
__device__ __forceinline__ u16 f2bf(float f) {
  __hip_bfloat16 b = __float2bfloat16(f);   // RNE
  union { __hip_bfloat16 b; u16 u; } c; c.b = b; return c.u;
}

// async global->LDS, 16B per lane, dest = uniform base + lane*16
__device__ __forceinline__ void async_load16(const void* g, void* l) {
  __builtin_amdgcn_global_load_lds(
      (const __attribute__((address_space(1))) unsigned int*)g,
      (__attribute__((address_space(3))) unsigned int*)l, 16, 0, 0);
}

// ---------------- CSR build ----------------------------------------------------------
__global__ void k_hist(const int* __restrict__ dst, int* __restrict__ cnt) {
  int i = blockIdx.x * blockDim.x + threadIdx.x;
  int stride = gridDim.x * blockDim.x;
  for (; i < NE; i += stride) atomicAdd(&cnt[dst[i]], 1);
}

#define SCAN_B 196   // ceil(50000/256)
__global__ void k_blksum(const int* __restrict__ cnt, int* __restrict__ bsum) {
  __shared__ int red[256];
  int b = blockIdx.x, t = threadIdx.x;
  int i = b * 256 + t;
  red[t] = (i < NN) ? cnt[i] : 0;
  __syncthreads();
  for (int s = 128; s > 0; s >>= 1) { if (t < s) red[t] += red[t + s]; __syncthreads(); }
  if (t == 0) bsum[b] = red[0];
}

__global__ void k_scanb(const int* __restrict__ bsum, int* __restrict__ boff,
                        int* __restrict__ rp) {
  __shared__ int buf[256];
  int t = threadIdx.x;
  int x = (t < SCAN_B) ? bsum[t] : 0;
  buf[t] = x;
  __syncthreads();
  for (int off = 1; off < 256; off <<= 1) {
    int y = (t >= off) ? buf[t - off] : 0;
    __syncthreads();
    buf[t] += y;
    __syncthreads();
  }
  if (t < SCAN_B) boff[t] = buf[t] - x;   // exclusive
  if (t == 0) rp[0] = 0;
}

// writes rp (inclusive, shifted) AND fill[] = exclusive prefix (for scatter)
__global__ void k_scanf(const int* __restrict__ cnt, const int* __restrict__ boff,
                        int* __restrict__ rp, int* __restrict__ fill) {
  __shared__ int buf[256];
  int b = blockIdx.x, t = threadIdx.x;
  int i = b * 256 + t;
  int x = (i < NN) ? cnt[i] : 0;
  buf[t] = x;
  __syncthreads();
  for (int off = 1; off < 256; off <<= 1) {
    int y = (t >= off) ? buf[t - off] : 0;
    __syncthreads();
    buf[t] += y;
    __syncthreads();
  }
  if (i < NN) {
    int incl = boff[b] + buf[t];
    rp[i + 1] = incl;
    fill[i] = incl - x;
  }
}

// edge meta: low16 = src (NN < 65536), high16 = bf16(val) -> fp32 via mask
__global__ void k_scatter(const int* __restrict__ src, const int* __restrict__ dst,
                          const float* __restrict__ vals, int* __restrict__ fill,
                          u32* __restrict__ em) {
  int i = blockIdx.x * blockDim.x + threadIdx.x;
  int stride = gridDim.x * blockDim.x;
  for (; i < NE; i += stride) {
    int p = atomicAdd(&fill[dst[i]], 1);
    em[p] = (u32)src[i] | ((u32)f2bf(vals[i]) << 16);
  }
}

// ---------------- fp32 -> bf16 bulk convert ------------------------------------------
__global__ void k_cvt_bf16(const float* __restrict__ x, u16* __restrict__ xb, int n4) {
  int i = blockIdx.x * blockDim.x + threadIdx.x;
  if (i < n4) {
    float4 v = *(const float4*)(x + (size_t)i * 4);
    u16x4 o;
    o[0] = f2bf(v.x); o[1] = f2bf(v.y); o[2] = f2bf(v.z); o[3] = f2bf(v.w);
    *(u16x4*)(xb + (size_t)i * 4) = o;
  }
}

// ---------------- W[K][N] fp32 -> Wt[N][K] bf16 --------------------------------------
__global__ void k_wt(const float* __restrict__ W, u16* __restrict__ Wt, int K, int N) {
  int idx = blockIdx.x * blockDim.x + threadIdx.x;
  if (idx < N * K) {
    int n = idx / K, k = idx % K;
    Wt[idx] = f2bf(W[(size_t)k * N + n]);
  }
}

// ---------------- bf16 MFMA GEMM (m97 pattern): C = bf16(A @ Bt^T + bias) ------------
__global__ __launch_bounds__(256, 2) void k_gemm_mfma(
    const u16* __restrict__ A, const u16* __restrict__ Bt,
    const float* __restrict__ bias, u16* __restrict__ C,
    int M, int K, int N)
{
  __shared__ __align__(16) u16 As[128 * 32];   // row-major [128][32]
  __shared__ __align__(16) u16 Bs[128 * 32];
  int tid = threadIdx.x;
  int bm = blockIdx.y * 128;
  int bn = blockIdx.x * 128;
  int wave = tid >> 6, lane = tid & 63;

  int lrow = lane >> 2, lcol = (lane & 3) * 8;
  int arow0 = wave * 32 + lrow;
  int arow1 = wave * 32 + 16 + lrow;
  int garow0 = bm + arow0; if (garow0 >= M) garow0 = M - 1;
  int garow1 = bm + arow1; if (garow1 >= M) garow1 = M - 1;
  const u16* Ap0 = A + (size_t)garow0 * K + lcol;
  const u16* Ap1 = A + (size_t)garow1 * K + lcol;
  const u16* Bp0 = Bt + (size_t)(bn + arow0) * K + lcol;
  const u16* Bp1 = Bt + (size_t)(bn + arow1) * K + lcol;
  u16* lA0 = &As[(wave * 32) * 32];
  u16* lA1 = &As[(wave * 32 + 16) * 32];
  u16* lB0 = &Bs[(wave * 32) * 32];
  u16* lB1 = &Bs[(wave * 32 + 16) * 32];

  int wm = (wave >> 1) * 64, wn = (wave & 1) * 64;
  int m16 = lane & 15, quad = lane >> 4;

  f32x4 zz = {0.f, 0.f, 0.f, 0.f};
  f32x4 acc[4][4];
#pragma unroll
  for (int i = 0; i < 4; i++)
#pragma unroll
    for (int j = 0; j < 4; j++) acc[i][j] = zz;

  for (int k0 = 0; k0 < K; k0 += 32) {
    async_load16(Ap0 + k0, lA0);
    async_load16(Ap1 + k0, lA1);
    async_load16(Bp0 + k0, lB0);
    async_load16(Bp1 + k0, lB1);
    __syncthreads();

    bf16x8 af[4], bw[4];
#pragma unroll
    for (int i = 0; i < 4; i++)
      af[i] = *(const bf16x8*)&As[(wm + i * 16 + m16) * 32 + quad * 8];
#pragma unroll
    for (int j = 0; j < 4; j++)
      bw[j] = *(const bf16x8*)&Bs[(wn + j * 16 + m16) * 32 + quad * 8];
#pragma unroll
    for (int i = 0; i < 4; i++)
#pragma unroll
      for (int j = 0; j < 4; j++)
        acc[i][j] = __builtin_amdgcn_mfma_f32_16x16x32_bf16(af[i], bw[j], acc[i][j], 0, 0, 0);
    __syncthreads();
  }

#pragma unroll
  for (int j = 0; j < 4; j++) {
    int col = bn + wn + j * 16 + m16;
    float bv = bias[col];
#pragma unroll
    for (int i = 0; i < 4; i++) {
      int rbase = bm + wm + i * 16 + quad * 4;
#pragma unroll
      for (int r = 0; r < 4; r++) {
        int row = rbase + r;
        if (row < M) C[(size_t)row * N + col] = f2bf(acc[i][j][r] + bv);
      }
    }
  }
}

// ---------------- CSR SPMM F=512: bf16 gather, fp32 acc, unroll-2, relu --------------
__global__ __launch_bounds__(256) void k_spmm512(
    const int* __restrict__ rp, const u32* __restrict__ em,
    const u16* __restrict__ Xb, u16* __restrict__ Hb)
{
  int wave = threadIdx.x >> 6, lane = threadIdx.x & 63;
  int r = blockIdx.x * 4 + wave;
  if (r >= NN) return;
  int e0 = rp[r], e1 = rp[r + 1];
  float acc0[8], acc1[8];
#pragma unroll
  for (int j = 0; j < 8; j++) { acc0[j] = 0.f; acc1[j] = 0.f; }
  const u16* Xl = Xb + lane * 8;
  int e = e0;
  for (; e + 2 <= e1; e += 2) {
    u32 m0 = em[e], m1 = em[e + 1];
    float v0 = __uint_as_float(m0 & 0xFFFF0000u);
    float v1 = __uint_as_float(m1 & 0xFFFF0000u);
    u16x8 x0 = *(const u16x8*)(Xl + (size_t)(m0 & 0xFFFFu) * 512);
    u16x8 x1 = *(const u16x8*)(Xl + (size_t)(m1 & 0xFFFFu) * 512);
#pragma unroll
    for (int j = 0; j < 8; j++) {
      acc0[j] += v0 * bf2f(x0[j]);
      acc1[j] += v1 * bf2f(x1[j]);
    }
  }
  if (e < e1) {
    u32 m0 = em[e];
    float v0 = __uint_as_float(m0 & 0xFFFF0000u);
    u16x8 x0 = *(const u16x8*)(Xl + (size_t)(m0 & 0xFFFFu) * 512);
#pragma unroll
    for (int j = 0; j < 8; j++) acc0[j] += v0 * bf2f(x0[j]);
  }
  u16x8 o;
#pragma unroll
  for (int j = 0; j < 8; j++) o[j] = f2bf(fmaxf(acc0[j] + acc1[j], 0.f));
  *(u16x8*)(Hb + (size_t)r * 512 + lane * 8) = o;
}

// ------- CSR SPMM F=256: bf16 gather, fp32 out + bf16 copy + row sum-of-squares ------
__global__ __launch_bounds__(256) void k_spmm256(
    const int* __restrict__ rp, const u32* __restrict__ em,
    const u16* __restrict__ Xb, float* __restrict__ Hf,
    u16* __restrict__ Hb3, float* __restrict__ hsq)
{
  int wave = threadIdx.x >> 6, lane = threadIdx.x & 63;
  int r = blockIdx.x * 4 + wave;
  if (r >= NN) return;
  int e0 = rp[r], e1 = rp[r + 1];
  float4 a0 = make_float4(0.f, 0.f, 0.f, 0.f);
  float4 a1 = make_float4(0.f, 0.f, 0.f, 0.f);
  const u16* Xl = Xb + lane * 4;
  int e = e0;
  for (; e + 2 <= e1; e += 2) {
    u32 m0 = em[e], m1 = em[e + 1];
    float v0 = __uint_as_float(m0 & 0xFFFF0000u);
    float v1 = __uint_as_float(m1 & 0xFFFF0000u);
    u16x4 x0 = *(const u16x4*)(Xl + (size_t)(m0 & 0xFFFFu) * 256);
    u16x4 x1 = *(const u16x4*)(Xl + (size_t)(m1 & 0xFFFFu) * 256);
    a0.x += v0 * bf2f(x0[0]); a0.y += v0 * bf2f(x0[1]);
    a0.z += v0 * bf2f(x0[2]); a0.w += v0 * bf2f(x0[3]);
    a1.x += v1 * bf2f(x1[0]); a1.y += v1 * bf2f(x1[1]);
    a1.z += v1 * bf2f(x1[2]); a1.w += v1 * bf2f(x1[3]);
  }
  if (e < e1) {
    u32 m0 = em[e];
    float v0 = __uint_as_float(m0 & 0xFFFF0000u);
    u16x4 x0 = *(const u16x4*)(Xl + (size_t)(m0 & 0xFFFFu) * 256);
    a0.x += v0 * bf2f(x0[0]); a0.y += v0 * bf2f(x0[1]);
    a0.z += v0 * bf2f(x0[2]); a0.w += v0 * bf2f(x0[3]);
  }
  float4 o;
  o.x = a0.x + a1.x; o.y = a0.y + a1.y; o.z = a0.z + a1.z; o.w = a0.w + a1.w;
  *(float4*)(Hf + (size_t)r * 256 + lane * 4) = o;
  u16x4 ob;
  ob[0] = f2bf(o.x); ob[1] = f2bf(o.y); ob[2] = f2bf(o.z); ob[3] = f2bf(o.w);
  *(u16x4*)(Hb3 + (size_t)r * 256 + lane * 4) = ob;
  float s = o.x * o.x + o.y * o.y + o.z * o.z + o.w * o.w;
#pragma unroll
  for (int m = 1; m < 64; m <<= 1) s += __shfl_xor(s, m);
  if (lane == 0) hsq[r] = s;
}

// ---------------- fused ssf: threshold + sparsify + colstats + sigma -----------------
__global__ void k_ssf(const float* __restrict__ ssf, const float* __restrict__ sigma,
                      float* __restrict__ o_ssf, float* __restrict__ csq,
                      float* __restrict__ cnm, float* __restrict__ o_sig)
{
  __shared__ float sv[NSSF * NCLASS];   // 64 KB
  __shared__ int red[256];
  int tid = threadIdx.x;
  for (int i = tid; i < NSSF * NCLASS; i += 256) sv[i] = ssf[i];
  __syncthreads();
  unsigned lo = 0u, hi = 0x7f800000u;
  while (lo < hi) {
    unsigned mid = lo + ((hi - lo) >> 1);
    int c = 0;
    for (int i = tid; i < NSSF * NCLASS; i += 256)
      c += ((__float_as_uint(sv[i]) & 0x7fffffffu) <= mid) ? 1 : 0;
    red[tid] = c;
    __syncthreads();
    for (int s = 128; s > 0; s >>= 1) {
      if (tid < s) red[tid] += red[tid + s];
      __syncthreads();
    }
    int total = red[0];
    __syncthreads();
    if (total >= KTH) hi = mid; else lo = mid + 1;
  }
  float t = __uint_as_float(lo);
  for (int i = tid; i < NSSF * NCLASS; i += 256) {
    float v = sv[i];
    v = (fabsf(v) >= t) ? v : 0.f;
    sv[i] = v;
    o_ssf[i] = v;
  }
  __syncthreads();
  if (tid < 64) {
    float s = 0.f;
    for (int k = 0; k < NSSF; k++) { float v = sv[k * NCLASS + tid]; s += v * v; }
    csq[tid] = s;
    cnm[tid] = fmaxf(sqrtf(s), 1e-6f);
  }
  if (tid == 0) o_sig[0] = sigma[0];
}

// ---------------- MFMA epilogue: out = hb@ssfT, dist, cosine, 2x log-softmax ---------
// 782 blocks x 256 thr; each wave computes a 16-row tile (N=64, K=256).
// ssf_sp^T staged bf16 in LDS [64][264] (pad 8 u16 -> 528B stride, conflict-light).
#define SSTR 264
__global__ __launch_bounds__(256) void k_epi(
    const u16* __restrict__ hb, const float* __restrict__ hsq,
    const float* __restrict__ ssf_sp, const float* __restrict__ colsq,
    const float* __restrict__ cn, float* __restrict__ outp,
    float* __restrict__ lossp)
{
  __shared__ __align__(16) u16 sT[64 * SSTR];   // 33 KB
  int tid = threadIdx.x;
  for (int i = tid; i < NCLASS * NSSF; i += 256) {
    int n = i & 63, k = i >> 6;                 // read ssf_sp[k][n] coalesced in n
    sT[n * SSTR + k] = f2bf(ssf_sp[i]);
  }
  __syncthreads();

  int wave = tid >> 6, lane = tid & 63;
  int m16 = lane & 15, quad = lane >> 4;
  int rb = blockIdx.x * 64 + wave * 16;

  int arow = rb + m16; if (arow >= NN) arow = NN - 1;   // clamp (tail)
  const u16* hp = hb + (size_t)arow * NSSF + quad * 8;
  bf16x8 a8[8];
#pragma unroll
  for (int ks = 0; ks < 8; ks++) a8[ks] = *(const bf16x8*)(hp + ks * 32);

  f32x4 zz = {0.f, 0.f, 0.f, 0.f};
  f32x4 acc[4];
#pragma unroll
  for (int j = 0; j < 4; j++) acc[j] = zz;
#pragma unroll
  for (int j = 0; j < 4; j++) {
    const u16* bp = &sT[(j * 16 + m16) * SSTR + quad * 8];
#pragma unroll
    for (int ks = 0; ks < 8; ks++) {
      bf16x8 b8 = *(const bf16x8*)(bp + ks * 32);
      acc[j] = __builtin_amdgcn_mfma_f32_16x16x32_bf16(a8[ks], b8, acc[j], 0, 0, 0);
    }
  }

  float csql[4], cnl[4];
#pragma unroll
  for (int j = 0; j < 4; j++) {
    int c = j * 16 + m16;
    csql[j] = colsq[c];
    cnl[j] = cn[c];
  }

#pragma unroll
  for (int reg = 0; reg < 4; reg++) {
    int row = rb + quad * 4 + reg;
    bool ok = row < NN;
    int rowc = ok ? row : NN - 1;
    float hs = hsq[rowc];
    float hn = fmaxf(sqrtf(hs), 1e-6f);
    float d[4], sm[4];
    float m1 = -3.4e38f, m2 = -3.4e38f;
#pragma unroll
    for (int j = 0; j < 4; j++) {
      float o = acc[j][reg];
      float sq = hs - 2.f * o + csql[j];
      d[j] = -sqrtf(fmaxf(sq, 1e-12f));
      sm[j] = o / (hn * cnl[j]);
      m1 = fmaxf(m1, d[j]);
      m2 = fmaxf(m2, sm[j]);
    }
#pragma unroll
    for (int msk = 1; msk < 16; msk <<= 1) {
      m1 = fmaxf(m1, __shfl_xor(m1, msk));
      m2 = fmaxf(m2, __shfl_xor(m2, msk));
    }
    float s1 = 0.f, s2 = 0.f;
#pragma unroll
    for (int j = 0; j < 4; j++) {
      s1 += expf(d[j] - m1);
      s2 += expf(sm[j] - m2);
    }
#pragma unroll
    for (int msk = 1; msk < 16; msk <<= 1) {
      s1 += __shfl_xor(s1, msk);
      s2 += __shfl_xor(s2, msk);
    }
    float l1 = logf(s1), l2 = logf(s2);
    if (ok) {
#pragma unroll
      for (int j = 0; j < 4; j++) {
        int c = j * 16 + m16;
        outp[(size_t)row * NCLASS + c] = acc[j][reg];
        lossp[(size_t)row * NCLASS + c] =
            0.5f * ((d[j] - m1 - l1) + (sm[j] - m2 - l2));
      }
    }
  }
}

extern "C" void kernel_launch(void* const* d_in, const int* in_sizes, int n_in,
                              void* d_out, int out_size, void* d_ws, size_t ws_size,
                              hipStream_t stream)
{
  (void)in_sizes; (void)n_in; (void)out_size; (void)ws_size;
  const float* x    = (const float*)d_in[0];
  const int*   src  = (const int*)  d_in[1];
  const int*   dst  = (const int*)  d_in[2];
  const float* vals = (const float*)d_in[3];
  const float* W1 = (const float*)d_in[4];
  const float* b1 = (const float*)d_in[5];
  const float* W2 = (const float*)d_in[6];
  const float* b2 = (const float*)d_in[7];
  const float* W3 = (const float*)d_in[8];
  const float* b3 = (const float*)d_in[9];
  const float* ssf   = (const float*)d_in[10];
  const float* sigma = (const float*)d_in[11];

  // output layout: out[50000,64] | ssf_sp[256,64] | h[50000,256] | loss[50000,64] | sigma
  float* outf   = (float*)d_out;
  float* o_out  = outf;
  float* o_ssf  = outf + (size_t)NN * NCLASS;
  float* o_h    = o_ssf + NSSF * NCLASS;
  float* o_loss = o_h + (size_t)NN * NSSF;
  float* o_sig  = o_loss + (size_t)NN * NCLASS;

  // workspace
  u16* Xb  = (u16*)d_ws;                       // [NN,512] bf16
  u16* Yb  = Xb + (size_t)NN * NFEAT;          // [NN,512]
  u16* Hb  = Yb + (size_t)NN * NHID;           // [NN,512]; layer3: bf16 h copy
  u16* W1t = Hb + (size_t)NN * NHID;
  u16* W2t = W1t + (size_t)NFEAT * NHID;
  u16* W3t = W2t + (size_t)NHID * NHID;
  int* cnt = (int*)(W3t + (size_t)NSSF * NHID);
  int* rp  = cnt + NN;
  u32* em  = (u32*)(rp + 50016);
  int* bsum = (int*)(em + NE);
  int* boff = bsum + 256;
  float* csq = (float*)(boff + 256);
  float* cnm = csq + 64;
  float* hsq = cnm + 64;   // [NN]

  // CSR build
  hipMemsetAsync(cnt, 0, NN * sizeof(int), stream);
  k_hist<<<1024, 256, 0, stream>>>(dst, cnt);
  k_blksum<<<SCAN_B, 256, 0, stream>>>(cnt, bsum);
  k_scanb<<<1, 256, 0, stream>>>(bsum, boff, rp);
  k_scanf<<<SCAN_B, 256, 0, stream>>>(cnt, boff, rp, cnt);  // cnt -> fill (in place)
  k_scatter<<<1024, 256, 0, stream>>>(src, dst, vals, cnt, em);

  // bf16 conversions
  k_cvt_bf16<<<(NN * NFEAT / 4 + 255) / 256, 256, 0, stream>>>(x, Xb, NN * NFEAT / 4);
  k_wt<<<(NFEAT * NHID + 255) / 256, 256, 0, stream>>>(W1, W1t, NFEAT, NHID);
  k_wt<<<(NHID * NHID + 255) / 256, 256, 0, stream>>>(W2, W2t, NHID, NHID);
  k_wt<<<(NHID * NSSF + 255) / 256, 256, 0, stream>>>(W3, W3t, NHID, NSSF);

  // 3 GCN layers
  k_gemm_mfma<<<dim3(4, 391), 256, 0, stream>>>(Xb, W1t, b1, Yb, NN, NFEAT, NHID);
  k_spmm512<<<NN / 4, 256, 0, stream>>>(rp, em, Yb, Hb);
  k_gemm_mfma<<<dim3(4, 391), 256, 0, stream>>>(Hb, W2t, b2, Yb, NN, NHID, NHID);
  k_spmm512<<<NN / 4, 256, 0, stream>>>(rp, em, Yb, Xb);   // Xb reused as H2
  k_gemm_mfma<<<dim3(2, 391), 256, 0, stream>>>(Xb, W3t, b3, Yb, NN, NHID, NSSF);
  k_spmm256<<<NN / 4, 256, 0, stream>>>(rp, em, Yb, o_h, Hb, hsq);  // Hb = bf16 h

  // SSF sparsify + MFMA epilogue
  k_ssf<<<1, 256, 0, stream>>>(ssf, sigma, o_ssf, csq, cnm, o_sig);
  k_epi<<<(NN + 63) / 64, 256, 0, stream>>>(Hb, hsq, o_ssf, csq, cnm, o_out, o_loss);
}

// Round 6
// 1169.166 us; speedup vs baseline: 1.6871x; 1.0053x over previous
//
#include <hip/hip_runtime.h>
#include <hip/hip_bf16.h>
#include <cstddef>

#define NN 50000
#define NE 1600000
#define NFEAT 512
#define NHID 512
#define NSSF 256
#define NCLASS 64
#define KTH 8193   // smallest u with count(|ssf|<=u) >= 8193  -> sorted[8192]

typedef unsigned short u16;
typedef unsigned int u32;
typedef u16 u16x8 __attribute__((ext_vector_type(8)));
typedef u16 u16x4 __attribute__((ext_vector_type(4)));
typedef short bf16x8 __attribute__((ext_vector_type(8)));
typedef float f32x4 __attribute__((ext_vector_type(4)));

__device__ __forceinline__ float bf2f(u16 u) {
  union { unsigned u; float f; } c; c.u = ((unsigned)u) << 16; return c.f;
}
__device__ __forceinline__ u16 f2bf(float f) {
  __hip_bfloat16 b = __float2bfloat16(f);   // RNE
  union { __hip_bfloat16 b; u16 u; } c; c.b = b; return c.u;
}

// async global->LDS, 16B per lane, dest = uniform base + lane*16
__device__ __forceinline__ void async_load16(const void* g, void* l) {
  __builtin_amdgcn_global_load_lds(
      (const __attribute__((address_space(1))) unsigned int*)g,
      (__attribute__((address_space(3))) unsigned int*)l, 16, 0, 0);
}

// ---------------- CSR build ----------------------------------------------------------
__global__ void k_hist(const int* __restrict__ dst, int* __restrict__ cnt) {
  int i = blockIdx.x * blockDim.x + threadIdx.x;
  int stride = gridDim.x * blockDim.x;
  for (; i < NE; i += stride) atomicAdd(&cnt[dst[i]], 1);
}

#define SCAN_B 196   // ceil(50000/256)
__global__ void k_blksum(const int* __restrict__ cnt, int* __restrict__ bsum) {
  __shared__ int red[256];
  int b = blockIdx.x, t = threadIdx.x;
  int i = b * 256 + t;
  red[t] = (i < NN) ? cnt[i] : 0;
  __syncthreads();
  for (int s = 128; s > 0; s >>= 1) { if (t < s) red[t] += red[t + s]; __syncthreads(); }
  if (t == 0) bsum[b] = red[0];
}

__global__ void k_scanb(const int* __restrict__ bsum, int* __restrict__ boff,
                        int* __restrict__ rp) {
  __shared__ int buf[256];
  int t = threadIdx.x;
  int x = (t < SCAN_B) ? bsum[t] : 0;
  buf[t] = x;
  __syncthreads();
  for (int off = 1; off < 256; off <<= 1) {
    int y = (t >= off) ? buf[t - off] : 0;
    __syncthreads();
    buf[t] += y;
    __syncthreads();
  }
  if (t < SCAN_B) boff[t] = buf[t] - x;   // exclusive
  if (t == 0) rp[0] = 0;
}

// writes rp (inclusive, shifted) AND fill[] = exclusive prefix (for scatter)
__global__ void k_scanf(const int* __restrict__ cnt, const int* __restrict__ boff,
                        int* __restrict__ rp, int* __restrict__ fill) {
  __shared__ int buf[256];
  int b = blockIdx.x, t = threadIdx.x;
  int i = b * 256 + t;
  int x = (i < NN) ? cnt[i] : 0;
  buf[t] = x;
  __syncthreads();
  for (int off = 1; off < 256; off <<= 1) {
    int y = (t >= off) ? buf[t - off] : 0;
    __syncthreads();
    buf[t] += y;
    __syncthreads();
  }
  if (i < NN) {
    int incl = boff[b] + buf[t];
    rp[i + 1] = incl;
    fill[i] = incl - x;
  }
}

// edge meta: low16 = src (NN < 65536), high16 = bf16(val) -> fp32 via mask
__global__ void k_scatter(const int* __restrict__ src, const int* __restrict__ dst,
                          const float* __restrict__ vals, int* __restrict__ fill,
                          u32* __restrict__ em) {
  int i = blockIdx.x * blockDim.x + threadIdx.x;
  int stride = gridDim.x * blockDim.x;
  for (; i < NE; i += stride) {
    int p = atomicAdd(&fill[dst[i]], 1);
    em[p] = (u32)src[i] | ((u32)f2bf(vals[i]) << 16);
  }
}

// ---------------- all 3 weights: W[K][N] fp32 -> Wt[N][K] bf16, one kernel -----------
__global__ void k_wt_all(const float* __restrict__ W1, const float* __restrict__ W2,
                         const float* __restrict__ W3, u16* __restrict__ W1t,
                         u16* __restrict__ W2t, u16* __restrict__ W3t) {
  int idx = blockIdx.x * blockDim.x + threadIdx.x;
  const int S1 = NFEAT * NHID;        // 262144, [512][512]
  const int S2 = S1 + NHID * NHID;    // + 262144
  const int S3 = S2 + NHID * NSSF;    // + 131072 (W3t is [256][512])
  if (idx < S1) {
    int n = idx >> 9, k = idx & 511;
    W1t[idx] = f2bf(W1[(size_t)k * NHID + n]);
  } else if (idx < S2) {
    int j = idx - S1;
    int n = j >> 9, k = j & 511;
    W2t[j] = f2bf(W2[(size_t)k * NHID + n]);
  } else if (idx < S3) {
    int j = idx - S2;
    int n = j >> 9, k = j & 511;     // n < 256, k < 512
    W3t[j] = f2bf(W3[(size_t)k * NSSF + n]);
  }
}

// ------- GEMM layer 1: A fp32 (x), staged via VGPR->bf16->LDS; B bf16 async ----------
// 128x128 tile, BK=32. As padded stride 40 u16 (80B rows, 16B-aligned, bank-spread).
__global__ __launch_bounds__(256, 2) void k_gemm_f32a(
    const float* __restrict__ A, const u16* __restrict__ Bt,
    const float* __restrict__ bias, u16* __restrict__ C,
    int M, int K, int N)
{
  __shared__ __align__(16) u16 As[128 * 40];   // 10.25 KB
  __shared__ __align__(16) u16 Bs[128 * 32];   // 8 KB
  int tid = threadIdx.x;
  int bm = blockIdx.y * 128;
  int bn = blockIdx.x * 128;
  int wave = tid >> 6, lane = tid & 63;

  // A staging: 1024 float4 chunks; thread t takes f = t + i*256, i<4.
  int arows[4], acol4[4];
  const float* Aps[4];
#pragma unroll
  for (int i = 0; i < 4; i++) {
    int f = tid + i * 256;
    int row = f >> 3, c4 = (f & 7) * 4;
    arows[i] = row; acol4[i] = c4;
    int gr = bm + row; if (gr >= M) gr = M - 1;
    Aps[i] = A + (size_t)gr * K + c4;
  }
  // B staging: async, wave covers rows [wave*32, wave*32+32)
  int lrow = lane >> 2, lcol = (lane & 3) * 8;
  const u16* Bp0 = Bt + (size_t)(bn + wave * 32 + lrow) * K + lcol;
  const u16* Bp1 = Bt + (size_t)(bn + wave * 32 + 16 + lrow) * K + lcol;
  u16* lB0 = &Bs[(wave * 32) * 32];
  u16* lB1 = &Bs[(wave * 32 + 16) * 32];

  int wm = (wave >> 1) * 64, wn = (wave & 1) * 64;
  int m16 = lane & 15, quad = lane >> 4;

  f32x4 zz = {0.f, 0.f, 0.f, 0.f};
  f32x4 acc[4][4];
#pragma unroll
  for (int i = 0; i < 4; i++)
#pragma unroll
    for (int j = 0; j < 4; j++) acc[i][j] = zz;

  for (int k0 = 0; k0 < K; k0 += 32) {
    async_load16(Bp0 + k0, lB0);
    async_load16(Bp1 + k0, lB1);
    float4 av[4];
#pragma unroll
    for (int i = 0; i < 4; i++) av[i] = *(const float4*)(Aps[i] + k0);
#pragma unroll
    for (int i = 0; i < 4; i++) {
      u16x4 o;
      o[0] = f2bf(av[i].x); o[1] = f2bf(av[i].y);
      o[2] = f2bf(av[i].z); o[3] = f2bf(av[i].w);
      *(u16x4*)&As[arows[i] * 40 + acol4[i]] = o;
    }
    __syncthreads();   // drains vmcnt (async B) + lgkm (A ds_writes)

    bf16x8 af[4], bw[4];
#pragma unroll
    for (int i = 0; i < 4; i++)
      af[i] = *(const bf16x8*)&As[(wm + i * 16 + m16) * 40 + quad * 8];
#pragma unroll
    for (int j = 0; j < 4; j++)
      bw[j] = *(const bf16x8*)&Bs[(wn + j * 16 + m16) * 32 + quad * 8];
#pragma unroll
    for (int i = 0; i < 4; i++)
#pragma unroll
      for (int j = 0; j < 4; j++)
        acc[i][j] = __builtin_amdgcn_mfma_f32_16x16x32_bf16(af[i], bw[j], acc[i][j], 0, 0, 0);
    __syncthreads();
  }

#pragma unroll
  for (int j = 0; j < 4; j++) {
    int col = bn + wn + j * 16 + m16;
    float bv = bias[col];
#pragma unroll
    for (int i = 0; i < 4; i++) {
      int rbase = bm + wm + i * 16 + quad * 4;
#pragma unroll
      for (int r = 0; r < 4; r++) {
        int row = rbase + r;
        if (row < M) C[(size_t)row * N + col] = f2bf(acc[i][j][r] + bv);
      }
    }
  }
}

// ---------------- bf16 MFMA GEMM (m97 pattern): C = bf16(A @ Bt^T + bias) ------------
__global__ __launch_bounds__(256, 2) void k_gemm_mfma(
    const u16* __restrict__ A, const u16* __restrict__ Bt,
    const float* __restrict__ bias, u16* __restrict__ C,
    int M, int K, int N)
{
  __shared__ __align__(16) u16 As[128 * 32];   // row-major [128][32]
  __shared__ __align__(16) u16 Bs[128 * 32];
  int tid = threadIdx.x;
  int bm = blockIdx.y * 128;
  int bn = blockIdx.x * 128;
  int wave = tid >> 6, lane = tid & 63;

  int lrow = lane >> 2, lcol = (lane & 3) * 8;
  int arow0 = wave * 32 + lrow;
  int arow1 = wave * 32 + 16 + lrow;
  int garow0 = bm + arow0; if (garow0 >= M) garow0 = M - 1;
  int garow1 = bm + arow1; if (garow1 >= M) garow1 = M - 1;
  const u16* Ap0 = A + (size_t)garow0 * K + lcol;
  const u16* Ap1 = A + (size_t)garow1 * K + lcol;
  const u16* Bp0 = Bt + (size_t)(bn + arow0) * K + lcol;
  const u16* Bp1 = Bt + (size_t)(bn + arow1) * K + lcol;
  u16* lA0 = &As[(wave * 32) * 32];
  u16* lA1 = &As[(wave * 32 + 16) * 32];
  u16* lB0 = &Bs[(wave * 32) * 32];
  u16* lB1 = &Bs[(wave * 32 + 16) * 32];

  int wm = (wave >> 1) * 64, wn = (wave & 1) * 64;
  int m16 = lane & 15, quad = lane >> 4;

  f32x4 zz = {0.f, 0.f, 0.f, 0.f};
  f32x4 acc[4][4];
#pragma unroll
  for (int i = 0; i < 4; i++)
#pragma unroll
    for (int j = 0; j < 4; j++) acc[i][j] = zz;

  for (int k0 = 0; k0 < K; k0 += 32) {
    async_load16(Ap0 + k0, lA0);
    async_load16(Ap1 + k0, lA1);
    async_load16(Bp0 + k0, lB0);
    async_load16(Bp1 + k0, lB1);
    __syncthreads();

    bf16x8 af[4], bw[4];
#pragma unroll
    for (int i = 0; i < 4; i++)
      af[i] = *(const bf16x8*)&As[(wm + i * 16 + m16) * 32 + quad * 8];
#pragma unroll
    for (int j = 0; j < 4; j++)
      bw[j] = *(const bf16x8*)&Bs[(wn + j * 16 + m16) * 32 + quad * 8];
#pragma unroll
    for (int i = 0; i < 4; i++)
#pragma unroll
      for (int j = 0; j < 4; j++)
        acc[i][j] = __builtin_amdgcn_mfma_f32_16x16x32_bf16(af[i], bw[j], acc[i][j], 0, 0, 0);
    __syncthreads();
  }

#pragma unroll
  for (int j = 0; j < 4; j++) {
    int col = bn + wn + j * 16 + m16;
    float bv = bias[col];
#pragma unroll
    for (int i = 0; i < 4; i++) {
      int rbase = bm + wm + i * 16 + quad * 4;
#pragma unroll
      for (int r = 0; r < 4; r++) {
        int row = rbase + r;
        if (row < M) C[(size_t)row * N + col] = f2bf(acc[i][j][r] + bv);
      }
    }
  }
}

// ---------------- CSR SPMM F=512: bf16 gather, fp32 acc, unroll-4, relu --------------
__global__ __launch_bounds__(256) void k_spmm512(
    const int* __restrict__ rp, const u32* __restrict__ em,
    const u16* __restrict__ Xb, u16* __restrict__ Hb)
{
  int wave = threadIdx.x >> 6, lane = threadIdx.x & 63;
  int r = blockIdx.x * 4 + wave;
  if (r >= NN) return;
  int e0 = rp[r], e1 = rp[r + 1];
  float acc0[8], acc1[8];
#pragma unroll
  for (int j = 0; j < 8; j++) { acc0[j] = 0.f; acc1[j] = 0.f; }
  const u16* Xl = Xb + lane * 8;
  int e = e0;
  for (; e + 4 <= e1; e += 4) {
    u32 m0 = em[e], m1 = em[e + 1], m2 = em[e + 2], m3 = em[e + 3];
    float v0 = __uint_as_float(m0 & 0xFFFF0000u);
    float v1 = __uint_as_float(m1 & 0xFFFF0000u);
    float v2 = __uint_as_float(m2 & 0xFFFF0000u);
    float v3 = __uint_as_float(m3 & 0xFFFF0000u);
    u16x8 x0 = *(const u16x8*)(Xl + (size_t)(m0 & 0xFFFFu) * 512);
    u16x8 x1 = *(const u16x8*)(Xl + (size_t)(m1 & 0xFFFFu) * 512);
    u16x8 x2 = *(const u16x8*)(Xl + (size_t)(m2 & 0xFFFFu) * 512);
    u16x8 x3 = *(const u16x8*)(Xl + (size_t)(m3 & 0xFFFFu) * 512);
#pragma unroll
    for (int j = 0; j < 8; j++) {
      acc0[j] += v0 * bf2f(x0[j]);
      acc1[j] += v1 * bf2f(x1[j]);
      acc0[j] += v2 * bf2f(x2[j]);
      acc1[j] += v3 * bf2f(x3[j]);
    }
  }
  for (; e < e1; ++e) {
    u32 m0 = em[e];
    float v0 = __uint_as_float(m0 & 0xFFFF0000u);
    u16x8 x0 = *(const u16x8*)(Xl + (size_t)(m0 & 0xFFFFu) * 512);
#pragma unroll
    for (int j = 0; j < 8; j++) acc0[j] += v0 * bf2f(x0[j]);
  }
  u16x8 o;
#pragma unroll
  for (int j = 0; j < 8; j++) o[j] = f2bf(fmaxf(acc0[j] + acc1[j], 0.f));
  *(u16x8*)(Hb + (size_t)r * 512 + lane * 8) = o;
}

// ------- CSR SPMM F=256: bf16 gather, fp32 out + bf16 copy + row sum-of-squares ------
__global__ __launch_bounds__(256) void k_spmm256(
    const int* __restrict__ rp, const u32* __restrict__ em,
    const u16* __restrict__ Xb, float* __restrict__ Hf,
    u16* __restrict__ Hb3, float* __restrict__ hsq)
{
  int wave = threadIdx.x >> 6, lane = threadIdx.x & 63;
  int r = blockIdx.x * 4 + wave;
  if (r >= NN) return;
  int e0 = rp[r], e1 = rp[r + 1];
  float4 a0 = make_float4(0.f, 0.f, 0.f, 0.f);
  float4 a1 = make_float4(0.f, 0.f, 0.f, 0.f);
  const u16* Xl = Xb + lane * 4;
  int e = e0;
  for (; e + 2 <= e1; e += 2) {
    u32 m0 = em[e], m1 = em[e + 1];
    float v0 = __uint_as_float(m0 & 0xFFFF0000u);
    float v1 = __uint_as_float(m1 & 0xFFFF0000u);
    u16x4 x0 = *(const u16x4*)(Xl + (size_t)(m0 & 0xFFFFu) * 256);
    u16x4 x1 = *(const u16x4*)(Xl + (size_t)(m1 & 0xFFFFu) * 256);
    a0.x += v0 * bf2f(x0[0]); a0.y += v0 * bf2f(x0[1]);
    a0.z += v0 * bf2f(x0[2]); a0.w += v0 * bf2f(x0[3]);
    a1.x += v1 * bf2f(x1[0]); a1.y += v1 * bf2f(x1[1]);
    a1.z += v1 * bf2f(x1[2]); a1.w += v1 * bf2f(x1[3]);
  }
  if (e < e1) {
    u32 m0 = em[e];
    float v0 = __uint_as_float(m0 & 0xFFFF0000u);
    u16x4 x0 = *(const u16x4*)(Xl + (size_t)(m0 & 0xFFFFu) * 256);
    a0.x += v0 * bf2f(x0[0]); a0.y += v0 * bf2f(x0[1]);
    a0.z += v0 * bf2f(x0[2]); a0.w += v0 * bf2f(x0[3]);
  }
  float4 o;
  o.x = a0.x + a1.x; o.y = a0.y + a1.y; o.z = a0.z + a1.z; o.w = a0.w + a1.w;
  *(float4*)(Hf + (size_t)r * 256 + lane * 4) = o;
  u16x4 ob;
  ob[0] = f2bf(o.x); ob[1] = f2bf(o.y); ob[2] = f2bf(o.z); ob[3] = f2bf(o.w);
  *(u16x4*)(Hb3 + (size_t)r * 256 + lane * 4) = ob;
  float s = o.x * o.x + o.y * o.y + o.z * o.z + o.w * o.w;
#pragma unroll
  for (int m = 1; m < 64; m <<= 1) s += __shfl_xor(s, m);
  if (lane == 0) hsq[r] = s;
}

// ---------------- fused ssf: threshold + sparsify + colstats + sigma -----------------
__global__ void k_ssf(const float* __restrict__ ssf, const float* __restrict__ sigma,
                      float* __restrict__ o_ssf, float* __restrict__ csq,
                      float* __restrict__ cnm, float* __restrict__ o_sig)
{
  __shared__ float sv[NSSF * NCLASS];   // 64 KB
  __shared__ int red[256];
  int tid = threadIdx.x;
  for (int i = tid; i < NSSF * NCLASS; i += 256) sv[i] = ssf[i];
  __syncthreads();
  unsigned lo = 0u, hi = 0x7f800000u;
  while (lo < hi) {
    unsigned mid = lo + ((hi - lo) >> 1);
    int c = 0;
    for (int i = tid; i < NSSF * NCLASS; i += 256)
      c += ((__float_as_uint(sv[i]) & 0x7fffffffu) <= mid) ? 1 : 0;
    red[tid] = c;
    __syncthreads();
    for (int s = 128; s > 0; s >>= 1) {
      if (tid < s) red[tid] += red[tid + s];
      __syncthreads();
    }
    int total = red[0];
    __syncthreads();
    if (total >= KTH) hi = mid; else lo = mid + 1;
  }
  float t = __uint_as_float(lo);
  for (int i = tid; i < NSSF * NCLASS; i += 256) {
    float v = sv[i];
    v = (fabsf(v) >= t) ? v : 0.f;
    sv[i] = v;
    o_ssf[i] = v;
  }
  __syncthreads();
  if (tid < 64) {
    float s = 0.f;
    for (int k = 0; k < NSSF; k++) { float v = sv[k * NCLASS + tid]; s += v * v; }
    csq[tid] = s;
    cnm[tid] = fmaxf(sqrtf(s), 1e-6f);
  }
  if (tid == 0) o_sig[0] = sigma[0];
}

// ---------------- MFMA epilogue: out = hb@ssfT, dist, cosine, 2x log-softmax ---------
#define SSTR 264
__global__ __launch_bounds__(256) void k_epi(
    const u16* __restrict__ hb, const float* __restrict__ hsq,
    const float* __restrict__ ssf_sp, const float* __restrict__ colsq,
    const float* __restrict__ cn, float* __restrict__ outp,
    float* __restrict__ lossp)
{
  __shared__ __align__(16) u16 sT[64 * SSTR];   // 33 KB
  int tid = threadIdx.x;
  for (int i = tid; i < NCLASS * NSSF; i += 256) {
    int n = i & 63, k = i >> 6;                 // read ssf_sp[k][n] coalesced in n
    sT[n * SSTR + k] = f2bf(ssf_sp[i]);
  }
  __syncthreads();

  int wave = tid >> 6, lane = tid & 63;
  int m16 = lane & 15, quad = lane >> 4;
  int rb = blockIdx.x * 64 + wave * 16;

  int arow = rb + m16; if (arow >= NN) arow = NN - 1;   // clamp (tail)
  const u16* hp = hb + (size_t)arow * NSSF + quad * 8;
  bf16x8 a8[8];
#pragma unroll
  for (int ks = 0; ks < 8; ks++) a8[ks] = *(const bf16x8*)(hp + ks * 32);

  f32x4 zz = {0.f, 0.f, 0.f, 0.f};
  f32x4 acc[4];
#pragma unroll
  for (int j = 0; j < 4; j++) acc[j] = zz;
#pragma unroll
  for (int j = 0; j < 4; j++) {
    const u16* bp = &sT[(j * 16 + m16) * SSTR + quad * 8];
#pragma unroll
    for (int ks = 0; ks < 8; ks++) {
      bf16x8 b8 = *(const bf16x8*)(bp + ks * 32);
      acc[j] = __builtin_amdgcn_mfma_f32_16x16x32_bf16(a8[ks], b8, acc[j], 0, 0, 0);
    }
  }

  float csql[4], cnl[4];
#pragma unroll
  for (int j = 0; j < 4; j++) {
    int c = j * 16 + m16;
    csql[j] = colsq[c];
    cnl[j] = cn[c];
  }

#pragma unroll
  for (int reg = 0; reg < 4; reg++) {
    int row = rb + quad * 4 + reg;
    bool ok = row < NN;
    int rowc = ok ? row : NN - 1;
    float hs = hsq[rowc];
    float hn = fmaxf(sqrtf(hs), 1e-6f);
    float d[4], sm[4];
    float m1 = -3.4e38f, m2 = -3.4e38f;
#pragma unroll
    for (int j = 0; j < 4; j++) {
      float o = acc[j][reg];
      float sq = hs - 2.f * o + csql[j];
      d[j] = -sqrtf(fmaxf(sq, 1e-12f));
      sm[j] = o / (hn * cnl[j]);
      m1 = fmaxf(m1, d[j]);
      m2 = fmaxf(m2, sm[j]);
    }
#pragma unroll
    for (int msk = 1; msk < 16; msk <<= 1) {
      m1 = fmaxf(m1, __shfl_xor(m1, msk));
      m2 = fmaxf(m2, __shfl_xor(m2, msk));
    }
    float s1 = 0.f, s2 = 0.f;
#pragma unroll
    for (int j = 0; j < 4; j++) {
      s1 += expf(d[j] - m1);
      s2 += expf(sm[j] - m2);
    }
#pragma unroll
    for (int msk = 1; msk < 16; msk <<= 1) {
      s1 += __shfl_xor(s1, msk);
      s2 += __shfl_xor(s2, msk);
    }
    float l1 = logf(s1), l2 = logf(s2);
    if (ok) {
#pragma unroll
      for (int j = 0; j < 4; j++) {
        int c = j * 16 + m16;
        outp[(size_t)row * NCLASS + c] = acc[j][reg];
        lossp[(size_t)row * NCLASS + c] =
            0.5f * ((d[j] - m1 - l1) + (sm[j] - m2 - l2));
      }
    }
  }
}

extern "C" void kernel_launch(void* const* d_in, const int* in_sizes, int n_in,
                              void* d_out, int out_size, void* d_ws, size_t ws_size,
                              hipStream_t stream)
{
  (void)in_sizes; (void)n_in; (void)out_size; (void)ws_size;
  const float* x    = (const float*)d_in[0];
  const int*   src  = (const int*)  d_in[1];
  const int*   dst  = (const int*)  d_in[2];
  const float* vals = (const float*)d_in[3];
  const float* W1 = (const float*)d_in[4];
  const float* b1 = (const float*)d_in[5];
  const float* W2 = (const float*)d_in[6];
  const float* b2 = (const float*)d_in[7];
  const float* W3 = (const float*)d_in[8];
  const float* b3 = (const float*)d_in[9];
  const float* ssf   = (const float*)d_in[10];
  const float* sigma = (const float*)d_in[11];

  // output layout: out[50000,64] | ssf_sp[256,64] | h[50000,256] | loss[50000,64] | sigma
  float* outf   = (float*)d_out;
  float* o_out  = outf;
  float* o_ssf  = outf + (size_t)NN * NCLASS;
  float* o_h    = o_ssf + NSSF * NCLASS;
  float* o_loss = o_h + (size_t)NN * NSSF;
  float* o_sig  = o_loss + (size_t)NN * NCLASS;

  // workspace
  u16* Xb  = (u16*)d_ws;                       // [NN,512] bf16 (layer-2 spmm output)
  u16* Yb  = Xb + (size_t)NN * NFEAT;          // [NN,512]
  u16* Hb  = Yb + (size_t)NN * NHID;           // [NN,512]; layer3: bf16 h copy
  u16* W1t = Hb + (size_t)NN * NHID;
  u16* W2t = W1t + (size_t)NFEAT * NHID;
  u16* W3t = W2t + (size_t)NHID * NHID;
  int* cnt = (int*)(W3t + (size_t)NSSF * NHID);
  int* rp  = cnt + NN;
  u32* em  = (u32*)(rp + 50016);
  int* bsum = (int*)(em + NE);
  int* boff = bsum + 256;
  float* csq = (float*)(boff + 256);
  float* cnm = csq + 64;
  float* hsq = cnm + 64;   // [NN]

  // CSR build
  hipMemsetAsync(cnt, 0, NN * sizeof(int), stream);
  k_hist<<<1024, 256, 0, stream>>>(dst, cnt);
  k_blksum<<<SCAN_B, 256, 0, stream>>>(cnt, bsum);
  k_scanb<<<1, 256, 0, stream>>>(bsum, boff, rp);
  k_scanf<<<SCAN_B, 256, 0, stream>>>(cnt, boff, rp, cnt);  // cnt -> fill (in place)
  k_scatter<<<1024, 256, 0, stream>>>(src, dst, vals, cnt, em);

  // weight transposes (single kernel)
  k_wt_all<<<(NFEAT * NHID * 2 + NHID * NSSF + 255) / 256, 256, 0, stream>>>(
      W1, W2, W3, W1t, W2t, W3t);

  // 3 GCN layers (layer-1 GEMM reads fp32 x directly)
  k_gemm_f32a<<<dim3(4, 391), 256, 0, stream>>>(x, W1t, b1, Yb, NN, NFEAT, NHID);
  k_spmm512<<<NN / 4, 256, 0, stream>>>(rp, em, Yb, Hb);
  k_gemm_mfma<<<dim3(4, 391), 256, 0, stream>>>(Hb, W2t, b2, Yb, NN, NHID, NHID);
  k_spmm512<<<NN / 4, 256, 0, stream>>>(rp, em, Yb, Xb);   // Xb = H2
  k_gemm_mfma<<<dim3(2, 391), 256, 0, stream>>>(Xb, W3t, b3, Yb, NN, NHID, NSSF);
  k_spmm256<<<NN / 4, 256, 0, stream>>>(rp, em, Yb, o_h, Hb, hsq);  // Hb = bf16 h

  // SSF sparsify + MFMA epilogue
  k_ssf<<<1, 256, 0, stream>>>(ssf, sigma, o_ssf, csq, cnm, o_sig);
  k_epi<<<(NN + 63) / 64, 256, 0, stream>>>(Hb, hsq, o_ssf, csq, cnm, o_out, o_loss);
}